// Round 4
// baseline (1111.924 us; speedup 1.0000x reference)
//
#include <hip/hip_runtime.h>
#include <math.h>

// ---------------------------------------------------------------------------
// Encoder block on MI355X (gfx950).  B=4, T=2048, E=1024, H=16, Dh=64, FF=4096.
// Inputs may be bf16 or fp32 (harness-dependent): a detector kernel classifies
// x's buffer; all compute kernels run on internal bf16.
// ---------------------------------------------------------------------------

using u16 = unsigned short;
typedef __bf16 bf16x8 __attribute__((ext_vector_type(8)));
typedef unsigned short u16x8 __attribute__((ext_vector_type(8)));
typedef unsigned short u16x4 __attribute__((ext_vector_type(4)));
typedef float f32x4 __attribute__((ext_vector_type(4)));

__device__ __forceinline__ float bf2f(u16 h) {
  return __uint_as_float(((unsigned int)h) << 16);
}
__device__ __forceinline__ u16 f2bf(float f) {  // RNE
  unsigned int u = __float_as_uint(f);
  u += 0x7fffu + ((u >> 16) & 1u);
  return (u16)(u >> 16);
}

__device__ __forceinline__ void gload_lds16(const void* g, void* l) {
  __builtin_amdgcn_global_load_lds(
      (__attribute__((address_space(1))) void*)(g),
      (__attribute__((address_space(3))) void*)(l), 16, 0, 0);
}

// ---------------------------------------------------------------------------
// Dtype detector: interpret first 2048 u16 of x as bf16; true-bf16 data is
// ~100% in [1e-4, 64]; fp32 data read as u16 pairs is ~54%.  flag=1 -> fp32.
// ---------------------------------------------------------------------------
__global__ __launch_bounds__(256) void detect_dtype(const u16* __restrict__ x,
                                                    int* __restrict__ flag) {
  __shared__ int cnt[256];
  int c = 0;
#pragma unroll
  for (int j = 0; j < 8; ++j) {
    float v = bf2f(x[threadIdx.x * 8 + j]);
    float a = fabsf(v);
    if (a >= 1e-4f && a <= 64.0f) ++c;  // NaN fails both -> not counted
  }
  cnt[threadIdx.x] = c;
  __syncthreads();
  if (threadIdx.x == 0) {
    int t = 0;
    for (int i = 0; i < 256; ++i) t += cnt[i];
    flag[0] = (t < 1638) ? 1 : 0;  // <80% in-range => fp32
  }
}

// ---------------------------------------------------------------------------
// Elementwise convert raw input -> bf16 (flag: 1=fp32 source, 0=bf16 copy).
// ---------------------------------------------------------------------------
__global__ __launch_bounds__(256) void cvt_copy(const void* __restrict__ in,
                                                u16* __restrict__ out,
                                                const int* __restrict__ flagp,
                                                long n) {
  long idx = ((long)blockIdx.x * 256 + threadIdx.x) * 4;
  if (idx >= n) return;
  if (*flagp) {
    float4 v = *(const float4*)((const float*)in + idx);
    out[idx] = f2bf(v.x); out[idx + 1] = f2bf(v.y);
    out[idx + 2] = f2bf(v.z); out[idx + 3] = f2bf(v.w);
  } else {
    *(u16x4*)(out + idx) = *(const u16x4*)((const u16*)in + idx);
  }
}

// 7 small vectors -> packed bf16 vec area. block = one vector.
__global__ __launch_bounds__(256) void cvt_vecs(
    const void* s0, const void* s1, const void* s2, const void* s3,
    const void* s4, const void* s5, const void* s6, u16* __restrict__ dst,
    const int* __restrict__ flagp) {
  const int lens[7] = {1024, 1024, 1024, 4096, 1024, 1024, 1024};
  const int offs[7] = {0, 1024, 2048, 3072, 7168, 8192, 9216};
  const void* srcs[7] = {s0, s1, s2, s3, s4, s5, s6};
  int w = blockIdx.x;
  int f = *flagp;
  for (int i = threadIdx.x; i < lens[w]; i += 256)
    dst[offs[w] + i] = f ? f2bf(((const float*)srcs[w])[i])
                         : ((const u16*)srcs[w])[i];
}

// ---------------------------------------------------------------------------
// Batched transpose + convert: out[b][c*R+r] = cvt(in[b][r*C+c]). R,C % 32 == 0.
// ---------------------------------------------------------------------------
__global__ __launch_bounds__(256) void transpose_cvt(
    const void* __restrict__ in, u16* __restrict__ out, int R, int C,
    long inBS, long outBS, const int* __restrict__ flagp) {
  __shared__ u16 tile[32][33];
  int f = *flagp;
  u16* ob = out + (long)blockIdx.z * outBS;
  int c = blockIdx.x * 32 + threadIdx.x;
  int r0 = blockIdx.y * 32;
  if (f) {
    const float* ib = (const float*)in + (long)blockIdx.z * inBS;
#pragma unroll
    for (int i = threadIdx.y; i < 32; i += 8)
      tile[i][threadIdx.x] = f2bf(ib[(long)(r0 + i) * C + c]);
  } else {
    const u16* ib = (const u16*)in + (long)blockIdx.z * inBS;
#pragma unroll
    for (int i = threadIdx.y; i < 32; i += 8)
      tile[i][threadIdx.x] = ib[(long)(r0 + i) * C + c];
  }
  __syncthreads();
  int r = r0 + threadIdx.x;
  int c0 = blockIdx.x * 32;
#pragma unroll
  for (int i = threadIdx.y; i < 32; i += 8)
    ob[(long)(c0 + i) * R + r] = tile[threadIdx.x][i];
}

// ---------------------------------------------------------------------------
// Stage V^T: vt[bh][d][t] = qkv[b*2048+t][2048 + h*64 + d].  32x32 tiles.
// Grid (T/32, 2, B*H), block (32,8).
// ---------------------------------------------------------------------------
__global__ __launch_bounds__(256) void vt_stage(const u16* __restrict__ qkv,
                                                u16* __restrict__ vt) {
  __shared__ u16 tile[32][33];
  const int bh = blockIdx.z;
  const int b = bh >> 4, h = bh & 15;
  const u16* ib = qkv + (long)(b * 2048) * 3072 + 2048 + h * 64;
  u16* ob = vt + (long)bh * 64 * 2048;
  int t0 = blockIdx.x * 32, d0 = blockIdx.y * 32;
  int d = d0 + threadIdx.x;
#pragma unroll
  for (int i = threadIdx.y; i < 32; i += 8)
    tile[i][threadIdx.x] = ib[(long)(t0 + i) * 3072 + d];
  __syncthreads();
  int t = t0 + threadIdx.x;
#pragma unroll
  for (int i = threadIdx.y; i < 32; i += 8)
    ob[(long)(d0 + i) * 2048 + t] = tile[threadIdx.x][i];
}

// ---------------------------------------------------------------------------
// GEMM: C[M,N] = A[M,K] @ Bt[N,K]^T (+ epilogue).  M,N % 128 == 0, K % 32 == 0.
// EPI 0: bf16 store.  EPI 1: +bias, f32 store.  EPI 2: +bias, gelu, bf16 store.
// m97 structure: 128x128 tile, BK=32, 4 waves x (4x4) mfma_f32_16x16x32_bf16.
// ---------------------------------------------------------------------------
template <int EPI>
__global__ __launch_bounds__(256) void gemm_bt(
    const u16* __restrict__ A, const u16* __restrict__ Bt,
    const u16* __restrict__ bias, void* __restrict__ Cout,
    int M, int N, int K) {
  __shared__ u16 As[128 * 32];
  __shared__ u16 Bs[128 * 32];
  const int tid = threadIdx.x;
  const int wave = tid >> 6, lane = tid & 63;
  const int m0 = blockIdx.x * 128, n0 = blockIdx.y * 128;
  const int wm = (wave >> 1) * 64, wn = (wave & 1) * 64;
  const int srow = lane >> 2, skoff = (lane & 3) * 8;

  const u16* ag[2];
  const u16* bg[2];
  u16* al[2];
  u16* bl[2];
#pragma unroll
  for (int p = 0; p < 2; ++p) {
    int r = p * 64 + wave * 16;
    ag[p] = A + (long)(m0 + r + srow) * K + skoff;
    bg[p] = Bt + (long)(n0 + r + srow) * K + skoff;
    al[p] = As + r * 32;  // wave-uniform LDS base (HW adds lane*16B)
    bl[p] = Bs + r * 32;
  }

  f32x4 acc[4][4] = {};
  const int lr = lane & 15, lk = (lane >> 4) * 8;

  for (int k0 = 0; k0 < K; k0 += 32) {
#pragma unroll
    for (int p = 0; p < 2; ++p) {
      gload_lds16(ag[p] + k0, al[p]);
      gload_lds16(bg[p] + k0, bl[p]);
    }
    __syncthreads();
    bf16x8 af[4], bfr[4];
#pragma unroll
    for (int t = 0; t < 4; ++t) {
      af[t] = *(const bf16x8*)(As + (wm + t * 16 + lr) * 32 + lk);
      bfr[t] = *(const bf16x8*)(Bs + (wn + t * 16 + lr) * 32 + lk);
    }
#pragma unroll
    for (int mt = 0; mt < 4; ++mt)
#pragma unroll
      for (int nt = 0; nt < 4; ++nt)
        acc[mt][nt] = __builtin_amdgcn_mfma_f32_16x16x32_bf16(
            af[mt], bfr[nt], acc[mt][nt], 0, 0, 0);
    __syncthreads();
  }

  // C/D layout (verified m89/m91): col = lane&15, row = (lane>>4)*4 + reg
  const int rq = (lane >> 4) * 4, cl = lane & 15;
#pragma unroll
  for (int mt = 0; mt < 4; ++mt)
#pragma unroll
    for (int nt = 0; nt < 4; ++nt) {
      int col = n0 + wn + nt * 16 + cl;
#pragma unroll
      for (int r = 0; r < 4; ++r) {
        long row = (long)(m0 + wm + mt * 16 + rq + r);
        float v = acc[mt][nt][r];
        if (EPI == 0) {
          ((u16*)Cout)[row * N + col] = f2bf(v);
        } else if (EPI == 1) {
          v += bf2f(bias[col]);
          ((float*)Cout)[row * N + col] = v;
        } else {
          v += bf2f(bias[col]);
          v = 0.5f * v * (1.0f + erff(v * 0.70710678118654752f));
          ((u16*)Cout)[row * N + col] = f2bf(v);
        }
      }
    }
}

// ---------------------------------------------------------------------------
// Flash attention v3.  qkv: [B*T,3072] bf16 (q|k|v), vt: [B*H,64,2048] bf16.
// cat: [B*T,1024] bf16.  Grid (T/64, B*H), block 256 (4 waves).
// No V LDS staging (V^T read direct from global); Ps double-buffered ->
// single barrier per 64-key iteration; Q pre-scaled by 1/8 (exact pow2).
// ---------------------------------------------------------------------------
__global__ __launch_bounds__(256) void flash_attn(
    const u16* __restrict__ qkv, const u16* __restrict__ vt,
    u16* __restrict__ cat) {
  const int T = 2048, LD = 3072;
  const int bh = blockIdx.y;
  const int b = bh >> 4, h = bh & 15;
  const int tid = threadIdx.x, wave = tid >> 6, lane = tid & 63;
  const int lr = lane & 15, lq = lane >> 4;

  __shared__ u16 Ps[2][64 * 72];  // [qrow][key], stride 72

  const u16* Qb = qkv + (long)(b * 2048) * LD + h * 64;
  const u16* Kb = Qb + 1024;
  const u16* Vt = vt + (long)bh * 64 * 2048;

  // Q A-fragments (A[m=lane&15][k=quad*8+j]), pre-scaled by 0.125 (exact)
  const int qrow = blockIdx.x * 64 + wave * 16 + lr;
  bf16x8 aq[2];
#pragma unroll
  for (int kt = 0; kt < 2; ++kt) {
    u16x8 q = *(const u16x8*)(Qb + (long)qrow * LD + kt * 32 + lq * 8);
    bf16x8 t;
#pragma unroll
    for (int j = 0; j < 8; ++j) t[j] = (__bf16)(bf2f(q[j]) * 0.125f);
    aq[kt] = t;
  }

  f32x4 o[4] = {};
  float m_i[4], l_i[4];
#pragma unroll
  for (int r = 0; r < 4; ++r) { m_i[r] = -1e30f; l_i[r] = 0.0f; }

  int sel = 0;
  for (int j0 = 0; j0 < T; j0 += 64, sel ^= 1) {
    // S strip = Qs @ K_tile^T  (B-frag n=key, k=d — K natural [t,d] layout)
    f32x4 s[4] = {};
#pragma unroll
    for (int nt = 0; nt < 4; ++nt)
#pragma unroll
      for (int kt = 0; kt < 2; ++kt) {
        bf16x8 bk = *(const bf16x8*)(Kb + (long)(j0 + nt * 16 + lr) * LD +
                                     kt * 32 + lq * 8);
        s[nt] = __builtin_amdgcn_mfma_f32_16x16x32_bf16(aq[kt], bk, s[nt], 0, 0, 0);
      }

    // online softmax; row r lives in reg r of 16-lane group lq
    float rowmax[4];
#pragma unroll
    for (int r = 0; r < 4; ++r)
      rowmax[r] = fmaxf(fmaxf(s[0][r], s[1][r]), fmaxf(s[2][r], s[3][r]));
#pragma unroll
    for (int off = 1; off < 16; off <<= 1)
#pragma unroll
      for (int r = 0; r < 4; ++r)
        rowmax[r] = fmaxf(rowmax[r], __shfl_xor(rowmax[r], off, 64));

    float alpha[4], rsum[4];
#pragma unroll
    for (int r = 0; r < 4; ++r) {
      float mn = fmaxf(m_i[r], rowmax[r]);
      alpha[r] = __expf(m_i[r] - mn);
      m_i[r] = mn;
    }
#pragma unroll
    for (int nt = 0; nt < 4; ++nt)
#pragma unroll
      for (int r = 0; r < 4; ++r) s[nt][r] = __expf(s[nt][r] - m_i[r]);
#pragma unroll
    for (int r = 0; r < 4; ++r)
      rsum[r] = s[0][r] + s[1][r] + s[2][r] + s[3][r];
#pragma unroll
    for (int off = 1; off < 16; off <<= 1)
#pragma unroll
      for (int r = 0; r < 4; ++r) rsum[r] += __shfl_xor(rsum[r], off, 64);
#pragma unroll
    for (int r = 0; r < 4; ++r) l_i[r] = l_i[r] * alpha[r] + rsum[r];
#pragma unroll
    for (int nt = 0; nt < 4; ++nt)
#pragma unroll
      for (int r = 0; r < 4; ++r) o[nt][r] *= alpha[r];

    // P (C-layout) -> LDS (buffer sel)
    const int prow = wave * 16 + lq * 4;
#pragma unroll
    for (int nt = 0; nt < 4; ++nt)
#pragma unroll
      for (int r = 0; r < 4; ++r)
        Ps[sel][(prow + r) * 72 + nt * 16 + lr] = f2bf(s[nt][r]);

    __syncthreads();  // orders iter-j P writes AND iter-(j-1) reads vs j+1

    // O += P @ V  (A-frag from Ps[sel]; B-frag n=d from global V^T rows)
    const int arow = wave * 16 + lr;
#pragma unroll
    for (int kt = 0; kt < 2; ++kt) {
      bf16x8 ap = *(const bf16x8*)(Ps[sel] + arow * 72 + kt * 32 + lq * 8);
#pragma unroll
      for (int nt = 0; nt < 4; ++nt) {
        bf16x8 bv = *(const bf16x8*)(Vt + (long)(nt * 16 + lr) * 2048 + j0 +
                                     kt * 32 + lq * 8);
        o[nt] = __builtin_amdgcn_mfma_f32_16x16x32_bf16(ap, bv, o[nt], 0, 0, 0);
      }
    }
  }

  // epilogue: O /= l, store cat[b, t, h*64 + d]
  const int trow = blockIdx.x * 64 + wave * 16 + lq * 4;
  u16* ob = cat + (long)(b * 2048) * 1024 + h * 64;
#pragma unroll
  for (int r = 0; r < 4; ++r) {
    float inv = 1.0f / l_i[r];
#pragma unroll
    for (int nt = 0; nt < 4; ++nt)
      ob[(long)(trow + r) * 1024 + nt * 16 + lr] = f2bf(o[nt][r] * inv);
  }
}

// ---------------------------------------------------------------------------
// out[row0+row] = res[row] + LN(y[row]) * g + b.  final_out: dtype per flag.
// ---------------------------------------------------------------------------
__global__ __launch_bounds__(256) void ln_residual(
    const float* __restrict__ y, const u16* __restrict__ res,
    const u16* __restrict__ g, const u16* __restrict__ bb,
    void* __restrict__ out, const int* __restrict__ flagp, int final_out,
    long row0) {
  const long row = blockIdx.x;
  const int tid = threadIdx.x, wave = tid >> 6, lane = tid & 63;
  float4 v = ((const float4*)(y + row * 1024))[tid];
  float s1 = v.x + v.y + v.z + v.w;
  float s2 = v.x * v.x + v.y * v.y + v.z * v.z + v.w * v.w;
#pragma unroll
  for (int off = 1; off < 64; off <<= 1) {
    s1 += __shfl_xor(s1, off, 64);
    s2 += __shfl_xor(s2, off, 64);
  }
  __shared__ float ws1[4], ws2[4];
  if (lane == 0) { ws1[wave] = s1; ws2[wave] = s2; }
  __syncthreads();
  float t1 = ws1[0] + ws1[1] + ws1[2] + ws1[3];
  float t2 = ws2[0] + ws2[1] + ws2[2] + ws2[3];
  float mu = t1 * (1.0f / 1024.0f);
  float var = t2 * (1.0f / 1024.0f) - mu * mu;
  float rstd = rsqrtf(var + 1e-5f);
  int i = tid * 4;
  float yy[4] = {v.x, v.y, v.z, v.w};
  bool f32out = final_out && (*flagp);
  long orow = row0 + row;
#pragma unroll
  for (int j = 0; j < 4; ++j) {
    float o = bf2f(res[row * 1024 + i + j]) +
              (yy[j] - mu) * rstd * bf2f(g[i + j]) + bf2f(bb[i + j]);
    if (f32out)
      ((float*)out)[orow * 1024 + i + j] = o;
    else
      ((u16*)out)[orow * 1024 + i + j] = f2bf(o);
  }
}

// ---------------------------------------------------------------------------
extern "C" void kernel_launch(void* const* d_in, const int* in_sizes, int n_in,
                              void* d_out, int out_size, void* d_ws,
                              size_t ws_size, hipStream_t stream) {
  const void* x_raw = d_in[0];
  const void* Wq = d_in[1];
  const void* Wk = d_in[2];
  const void* Wv = d_in[3];
  const void* Wo = d_in[4];
  const void* bo = d_in[5];
  const void* ln1g = d_in[6];
  const void* ln1b = d_in[7];
  const void* W1 = d_in[8];
  const void* b1 = d_in[9];
  const void* W2 = d_in[10];
  const void* b2 = d_in[11];
  const void* ln2g = d_in[12];
  const void* ln2b = d_in[13];

  char* ws = (char*)d_ws;
  // Region R0 [0,48MB): qkv bf16 -> mha f32 (32MB) -> h1c bf16(32MB)+ffc f32(16MB)
  u16* qkv = (u16*)(ws + 0);              // [8192,3072]
  float* mha = (float*)(ws + 0);          // [8192,1024]
  u16* h1c = (u16*)(ws + 0);              // [4096,4096] chunk
  float* ffc = (float*)(ws + 33554432);   // [4096,1024] chunk
  u16* cat = (u16*)(ws + 50331648);       // [8192,1024]
  u16* x1 = (u16*)(ws + 67108864);        // [8192,1024] (after flash)
  u16* vtb = (u16*)(ws + 67108864);       // [64,64,2048] V^T (dead before x1)
  u16* xb = (u16*)(ws + 83886080);        // [8192,1024] bf16-normalized x
  u16* wqkvt = (u16*)(ws + 100663296);    // [3072,1024]
  u16* wot = (u16*)(ws + 106954752);      // [1024,1024]
  u16* w1t = (u16*)(ws + 109051904);      // [4096,1024]
  u16* w2t = (u16*)(ws + 117440512);      // [1024,4096]
  u16* vecs = (u16*)(ws + 125829120);     // packed bias/gain vectors (bf16)
  int* flag = (int*)(ws + 125853696);     // dtype flag (1 = fp32 inputs)
  // total 125857800 B (~120 MB)

  const u16* v_bo = vecs + 0;
  const u16* v_l1g = vecs + 1024;
  const u16* v_l1b = vecs + 2048;
  const u16* v_b1 = vecs + 3072;
  const u16* v_b2 = vecs + 7168;
  const u16* v_l2g = vecs + 8192;
  const u16* v_l2b = vecs + 9216;

  detect_dtype<<<1, 256, 0, stream>>>((const u16*)x_raw, flag);
  cvt_copy<<<8192, 256, 0, stream>>>(x_raw, xb, flag, 8388608L);
  cvt_vecs<<<7, 256, 0, stream>>>(bo, ln1g, ln1b, b1, b2, ln2g, ln2b, vecs, flag);

  dim3 tb(32, 8);
  // Wq/Wk/Wv per-head [1024,64] -> [64,1024]; qkv col = {q,k,v}*1024 + h*64 + d
  transpose_cvt<<<dim3(2, 32, 16), tb, 0, stream>>>(Wq, wqkvt, 1024, 64, 65536, 65536, flag);
  transpose_cvt<<<dim3(2, 32, 16), tb, 0, stream>>>(Wk, wqkvt + 1048576, 1024, 64, 65536, 65536, flag);
  transpose_cvt<<<dim3(2, 32, 16), tb, 0, stream>>>(Wv, wqkvt + 2097152, 1024, 64, 65536, 65536, flag);
  transpose_cvt<<<dim3(32, 32, 1), tb, 0, stream>>>(Wo, wot, 1024, 1024, 0, 0, flag);
  transpose_cvt<<<dim3(128, 32, 1), tb, 0, stream>>>(W1, w1t, 1024, 4096, 0, 0, flag);
  transpose_cvt<<<dim3(32, 128, 1), tb, 0, stream>>>(W2, w2t, 4096, 1024, 0, 0, flag);

  // qkv = xb @ Wqkv
  gemm_bt<0><<<dim3(64, 24), 256, 0, stream>>>(xb, wqkvt, nullptr, qkv, 8192, 3072, 1024);
  // V^T staging for attention's PV B-fragments
  vt_stage<<<dim3(64, 2, 64), tb, 0, stream>>>(qkv, vtb);
  // cat = attention(qkv, vt)
  flash_attn<<<dim3(32, 64), 256, 0, stream>>>(qkv, vtb, cat);
  // mha = cat @ Wo + bo (f32)
  gemm_bt<1><<<dim3(64, 8), 256, 0, stream>>>(cat, wot, v_bo, mha, 8192, 1024, 1024);
  // x1 = xb + LN(mha)
  ln_residual<<<8192, 256, 0, stream>>>(mha, xb, v_l1g, v_l1b, x1, flag, 0, 0);

  // FFN in 2 row-chunks of 4096 (fits dead qkv region)
  for (int c = 0; c < 2; ++c) {
    const u16* x1c = x1 + (long)c * 4096 * 1024;
    gemm_bt<2><<<dim3(32, 32), 256, 0, stream>>>(x1c, w1t, v_b1, h1c, 4096, 4096, 1024);
    gemm_bt<1><<<dim3(32, 8), 256, 0, stream>>>(h1c, w2t, v_b2, ffc, 4096, 1024, 4096);
    ln_residual<<<4096, 256, 0, stream>>>(ffc, x1c, v_l2g, v_l2b, d_out, flag, 1,
                                          (long)c * 4096);
  }
}

// Round 5
// 858.787 us; speedup vs baseline: 1.2948x; 1.2948x over previous
//
#include <hip/hip_runtime.h>
#include <math.h>

// ---------------------------------------------------------------------------
// Encoder block on MI355X (gfx950).  B=4, T=2048, E=1024, H=16, Dh=64, FF=4096.
// Inputs may be bf16 or fp32 (harness-dependent, detector-classified).
// Attention v5: barrier-free flash loop, K/V pre-swizzled into MFMA B-fragment
// order (all inner-loop global loads fully coalesced), 32 Q-rows per wave.
// ---------------------------------------------------------------------------

using u16 = unsigned short;
typedef __bf16 bf16x8 __attribute__((ext_vector_type(8)));
typedef unsigned short u16x8 __attribute__((ext_vector_type(8)));
typedef unsigned short u16x4 __attribute__((ext_vector_type(4)));
typedef float f32x4 __attribute__((ext_vector_type(4)));

__device__ __forceinline__ float bf2f(u16 h) {
  return __uint_as_float(((unsigned int)h) << 16);
}
__device__ __forceinline__ u16 f2bf(float f) {  // RNE
  unsigned int u = __float_as_uint(f);
  u += 0x7fffu + ((u >> 16) & 1u);
  return (u16)(u >> 16);
}

__device__ __forceinline__ void gload_lds16(const void* g, void* l) {
  __builtin_amdgcn_global_load_lds(
      (__attribute__((address_space(1))) void*)(g),
      (__attribute__((address_space(3))) void*)(l), 16, 0, 0);
}

// ---------------------------------------------------------------------------
// Dtype detector (flag=1 -> fp32 inputs).
// ---------------------------------------------------------------------------
__global__ __launch_bounds__(256) void detect_dtype(const u16* __restrict__ x,
                                                    int* __restrict__ flag) {
  __shared__ int cnt[256];
  int c = 0;
#pragma unroll
  for (int j = 0; j < 8; ++j) {
    float v = bf2f(x[threadIdx.x * 8 + j]);
    float a = fabsf(v);
    if (a >= 1e-4f && a <= 64.0f) ++c;
  }
  cnt[threadIdx.x] = c;
  __syncthreads();
  if (threadIdx.x == 0) {
    int t = 0;
    for (int i = 0; i < 256; ++i) t += cnt[i];
    flag[0] = (t < 1638) ? 1 : 0;
  }
}

__global__ __launch_bounds__(256) void cvt_copy(const void* __restrict__ in,
                                                u16* __restrict__ out,
                                                const int* __restrict__ flagp,
                                                long n) {
  long idx = ((long)blockIdx.x * 256 + threadIdx.x) * 4;
  if (idx >= n) return;
  if (*flagp) {
    float4 v = *(const float4*)((const float*)in + idx);
    out[idx] = f2bf(v.x); out[idx + 1] = f2bf(v.y);
    out[idx + 2] = f2bf(v.z); out[idx + 3] = f2bf(v.w);
  } else {
    *(u16x4*)(out + idx) = *(const u16x4*)((const u16*)in + idx);
  }
}

__global__ __launch_bounds__(256) void cvt_vecs(
    const void* s0, const void* s1, const void* s2, const void* s3,
    const void* s4, const void* s5, const void* s6, u16* __restrict__ dst,
    const int* __restrict__ flagp) {
  const int lens[7] = {1024, 1024, 1024, 4096, 1024, 1024, 1024};
  const int offs[7] = {0, 1024, 2048, 3072, 7168, 8192, 9216};
  const void* srcs[7] = {s0, s1, s2, s3, s4, s5, s6};
  int w = blockIdx.x;
  int f = *flagp;
  for (int i = threadIdx.x; i < lens[w]; i += 256)
    dst[offs[w] + i] = f ? f2bf(((const float*)srcs[w])[i])
                         : ((const u16*)srcs[w])[i];
}

// ---------------------------------------------------------------------------
// Batched transpose + convert: out[b][c*R+r] = cvt(in[b][r*C+c]).
// ---------------------------------------------------------------------------
__global__ __launch_bounds__(256) void transpose_cvt(
    const void* __restrict__ in, u16* __restrict__ out, int R, int C,
    long inBS, long outBS, const int* __restrict__ flagp) {
  __shared__ u16 tile[32][33];
  int f = *flagp;
  u16* ob = out + (long)blockIdx.z * outBS;
  int c = blockIdx.x * 32 + threadIdx.x;
  int r0 = blockIdx.y * 32;
  if (f) {
    const float* ib = (const float*)in + (long)blockIdx.z * inBS;
#pragma unroll
    for (int i = threadIdx.y; i < 32; i += 8)
      tile[i][threadIdx.x] = f2bf(ib[(long)(r0 + i) * C + c]);
  } else {
    const u16* ib = (const u16*)in + (long)blockIdx.z * inBS;
#pragma unroll
    for (int i = threadIdx.y; i < 32; i += 8)
      tile[i][threadIdx.x] = ib[(long)(r0 + i) * C + c];
  }
  __syncthreads();
  int r = r0 + threadIdx.x;
  int c0 = blockIdx.x * 32;
#pragma unroll
  for (int i = threadIdx.y; i < 32; i += 8)
    ob[(long)(c0 + i) * R + r] = tile[threadIdx.x][i];
}

// ---------------------------------------------------------------------------
// Pre-swizzle K and V into MFMA B-fragment order.
// KF/VF layout: [(bh*32 + jblk)*8 + f][lane][8] u16, f = kt*4 + nt.
//   KF elem j = K[b, t=j0+nt*16+(lane&15), d=kt*32+(lane>>4)*8+j]
//   VF elem j = V[b, t=j0+kt*32+(lane>>4)*8+j, d=nt*16+(lane&15)]
// Grid (32 jblk, 64 bh), block 256.
// ---------------------------------------------------------------------------
__global__ __launch_bounds__(256) void kv_frag(const u16* __restrict__ qkv,
                                               u16* __restrict__ KF,
                                               u16* __restrict__ VF) {
  __shared__ u16 Kt[64][72];
  __shared__ u16 Vt[64][72];
  const int jblk = blockIdx.x, bh = blockIdx.y;
  const int b = bh >> 4, h = bh & 15;
  const int tid = threadIdx.x;
  const long j0 = jblk * 64;

  {  // stage 64x64 K and V tiles ([t][d] natural layout)
    int tt = tid >> 2, c0 = (tid & 3) * 16;
    const u16* src = qkv + (long)(b * 2048 + j0 + tt) * 3072 + h * 64 + c0;
    *(u16x8*)(&Kt[tt][c0]) = *(const u16x8*)(src + 1024);
    *(u16x8*)(&Kt[tt][c0 + 8]) = *(const u16x8*)(src + 1024 + 8);
    *(u16x8*)(&Vt[tt][c0]) = *(const u16x8*)(src + 2048);
    *(u16x8*)(&Vt[tt][c0 + 8]) = *(const u16x8*)(src + 2048 + 8);
  }
  __syncthreads();

  long obase = ((long)bh * 32 + jblk) * 8 * 512;
#pragma unroll
  for (int si = 0; si < 2; ++si) {
    int s = tid * 2 + si;           // slot 0..511
    int f = s >> 6, ln = s & 63;
    int kt = f >> 2, nt = f & 3;
    int lr = ln & 15, lq = ln >> 4;
    u16x8 ko, vo;
#pragma unroll
    for (int j = 0; j < 8; ++j) {
      ko[j] = Kt[nt * 16 + lr][kt * 32 + lq * 8 + j];
      vo[j] = Vt[kt * 32 + lq * 8 + j][nt * 16 + lr];
    }
    *(u16x8*)(KF + obase + (long)s * 8) = ko;
    *(u16x8*)(VF + obase + (long)s * 8) = vo;
  }
}

// ---------------------------------------------------------------------------
// GEMM: C[M,N] = A[M,K] @ Bt[N,K]^T (+ epilogue).  m97 structure.
// EPI 0: bf16 store.  EPI 1: +bias, f32 store.  EPI 2: +bias, gelu, bf16 store.
// ---------------------------------------------------------------------------
template <int EPI>
__global__ __launch_bounds__(256) void gemm_bt(
    const u16* __restrict__ A, const u16* __restrict__ Bt,
    const u16* __restrict__ bias, void* __restrict__ Cout,
    int M, int N, int K) {
  __shared__ u16 As[128 * 32];
  __shared__ u16 Bs[128 * 32];
  const int tid = threadIdx.x;
  const int wave = tid >> 6, lane = tid & 63;
  const int m0 = blockIdx.x * 128, n0 = blockIdx.y * 128;
  const int wm = (wave >> 1) * 64, wn = (wave & 1) * 64;
  const int srow = lane >> 2, skoff = (lane & 3) * 8;

  const u16* ag[2];
  const u16* bg[2];
  u16* al[2];
  u16* bl[2];
#pragma unroll
  for (int p = 0; p < 2; ++p) {
    int r = p * 64 + wave * 16;
    ag[p] = A + (long)(m0 + r + srow) * K + skoff;
    bg[p] = Bt + (long)(n0 + r + srow) * K + skoff;
    al[p] = As + r * 32;
    bl[p] = Bs + r * 32;
  }

  f32x4 acc[4][4] = {};
  const int lr = lane & 15, lk = (lane >> 4) * 8;

  for (int k0 = 0; k0 < K; k0 += 32) {
#pragma unroll
    for (int p = 0; p < 2; ++p) {
      gload_lds16(ag[p] + k0, al[p]);
      gload_lds16(bg[p] + k0, bl[p]);
    }
    __syncthreads();
    bf16x8 af[4], bfr[4];
#pragma unroll
    for (int t = 0; t < 4; ++t) {
      af[t] = *(const bf16x8*)(As + (wm + t * 16 + lr) * 32 + lk);
      bfr[t] = *(const bf16x8*)(Bs + (wn + t * 16 + lr) * 32 + lk);
    }
#pragma unroll
    for (int mt = 0; mt < 4; ++mt)
#pragma unroll
      for (int nt = 0; nt < 4; ++nt)
        acc[mt][nt] = __builtin_amdgcn_mfma_f32_16x16x32_bf16(
            af[mt], bfr[nt], acc[mt][nt], 0, 0, 0);
    __syncthreads();
  }

  const int rq = (lane >> 4) * 4, cl = lane & 15;
#pragma unroll
  for (int mt = 0; mt < 4; ++mt)
#pragma unroll
    for (int nt = 0; nt < 4; ++nt) {
      int col = n0 + wn + nt * 16 + cl;
#pragma unroll
      for (int r = 0; r < 4; ++r) {
        long row = (long)(m0 + wm + mt * 16 + rq + r);
        float v = acc[mt][nt][r];
        if (EPI == 0) {
          ((u16*)Cout)[row * N + col] = f2bf(v);
        } else if (EPI == 1) {
          v += bf2f(bias[col]);
          ((float*)Cout)[row * N + col] = v;
        } else {
          v += bf2f(bias[col]);
          v = 0.5f * v * (1.0f + erff(v * 0.70710678118654752f));
          ((u16*)Cout)[row * N + col] = f2bf(v);
        }
      }
    }
}

// ---------------------------------------------------------------------------
// Flash attention v5.  Barrier-free; K/V from fragment-order global buffers.
// Grid (T/128, B*H), block 256 (4 waves); each wave: 32 Q-rows (2 strips).
// ---------------------------------------------------------------------------
__global__ __launch_bounds__(256) void flash_attn(
    const u16* __restrict__ qkv, const u16* __restrict__ KF,
    const u16* __restrict__ VF, u16* __restrict__ cat) {
  const int T = 2048, LD = 3072;
  const int bh = blockIdx.y;
  const int b = bh >> 4, h = bh & 15;
  const int tid = threadIdx.x, wave = tid >> 6, lane = tid & 63;
  const int lr = lane & 15, lq = lane >> 4;

  __shared__ u16 Ps[4 * 32 * 72];  // per-wave 32 rows x 64 keys (stride 72)
  u16* Pw = Ps + wave * 32 * 72;

  const u16* Qb = qkv + (long)(b * 2048) * LD + h * 64;
  const long fbase = (long)bh * 32 * 8 * 512;

  // Q A-fragments for 2 strips, pre-scaled by 1/8 (exact)
  bf16x8 aq[2][2];
#pragma unroll
  for (int st = 0; st < 2; ++st) {
    int qrow = blockIdx.x * 128 + wave * 32 + st * 16 + lr;
#pragma unroll
    for (int kt = 0; kt < 2; ++kt) {
      u16x8 q = *(const u16x8*)(Qb + (long)qrow * LD + kt * 32 + lq * 8);
      bf16x8 t;
#pragma unroll
      for (int j = 0; j < 8; ++j) t[j] = (__bf16)(bf2f(q[j]) * 0.125f);
      aq[st][kt] = t;
    }
  }

  f32x4 o[2][4] = {};
  float m_i[2][4], l_i[2][4];
#pragma unroll
  for (int st = 0; st < 2; ++st)
#pragma unroll
    for (int r = 0; r < 4; ++r) { m_i[st][r] = -1e30f; l_i[st][r] = 0.0f; }

  for (int jblk = 0; jblk < T / 64; ++jblk) {
    const u16* kf = KF + fbase + (long)jblk * 8 * 512;
    const u16* vf = VF + fbase + (long)jblk * 8 * 512;

    // K fragments (coalesced 16B/lane), shared across both strips
    bf16x8 bk[2][4];
#pragma unroll
    for (int kt = 0; kt < 2; ++kt)
#pragma unroll
      for (int nt = 0; nt < 4; ++nt)
        bk[kt][nt] = *(const bf16x8*)(kf + (kt * 4 + nt) * 512 + lane * 8);

    f32x4 s[2][4] = {};
#pragma unroll
    for (int st = 0; st < 2; ++st)
#pragma unroll
      for (int nt = 0; nt < 4; ++nt)
#pragma unroll
        for (int kt = 0; kt < 2; ++kt)
          s[st][nt] = __builtin_amdgcn_mfma_f32_16x16x32_bf16(
              aq[st][kt], bk[kt][nt], s[st][nt], 0, 0, 0);

    // online softmax per strip (rows r of 16-lane group lq)
#pragma unroll
    for (int st = 0; st < 2; ++st) {
      float rowmax[4];
#pragma unroll
      for (int r = 0; r < 4; ++r)
        rowmax[r] = fmaxf(fmaxf(s[st][0][r], s[st][1][r]),
                          fmaxf(s[st][2][r], s[st][3][r]));
#pragma unroll
      for (int off = 1; off < 16; off <<= 1)
#pragma unroll
        for (int r = 0; r < 4; ++r)
          rowmax[r] = fmaxf(rowmax[r], __shfl_xor(rowmax[r], off, 64));

      float alpha[4], rsum[4];
#pragma unroll
      for (int r = 0; r < 4; ++r) {
        float mn = fmaxf(m_i[st][r], rowmax[r]);
        alpha[r] = __expf(m_i[st][r] - mn);
        m_i[st][r] = mn;
      }
#pragma unroll
      for (int nt = 0; nt < 4; ++nt)
#pragma unroll
        for (int r = 0; r < 4; ++r)
          s[st][nt][r] = __expf(s[st][nt][r] - m_i[st][r]);
#pragma unroll
      for (int r = 0; r < 4; ++r)
        rsum[r] = s[st][0][r] + s[st][1][r] + s[st][2][r] + s[st][3][r];
#pragma unroll
      for (int off = 1; off < 16; off <<= 1)
#pragma unroll
        for (int r = 0; r < 4; ++r) rsum[r] += __shfl_xor(rsum[r], off, 64);
#pragma unroll
      for (int r = 0; r < 4; ++r)
        l_i[st][r] = l_i[st][r] * alpha[r] + rsum[r];
#pragma unroll
      for (int nt = 0; nt < 4; ++nt)
#pragma unroll
        for (int r = 0; r < 4; ++r) o[st][nt][r] *= alpha[r];

      // P -> wave-private LDS (no barrier: same wave writes & reads)
#pragma unroll
      for (int nt = 0; nt < 4; ++nt)
#pragma unroll
        for (int r = 0; r < 4; ++r)
          Pw[(st * 16 + lq * 4 + r) * 72 + nt * 16 + lr] =
              f2bf(s[st][nt][r]);
    }

    // V fragments (coalesced), shared across strips
    bf16x8 bv[2][4];
#pragma unroll
    for (int kt = 0; kt < 2; ++kt)
#pragma unroll
      for (int nt = 0; nt < 4; ++nt)
        bv[kt][nt] = *(const bf16x8*)(vf + (kt * 4 + nt) * 512 + lane * 8);

    // O += P @ V
#pragma unroll
    for (int st = 0; st < 2; ++st)
#pragma unroll
      for (int kt = 0; kt < 2; ++kt) {
        bf16x8 ap = *(const bf16x8*)(Pw + (st * 16 + lr) * 72 + kt * 32 + lq * 8);
#pragma unroll
        for (int nt = 0; nt < 4; ++nt)
          o[st][nt] = __builtin_amdgcn_mfma_f32_16x16x32_bf16(
              ap, bv[kt][nt], o[st][nt], 0, 0, 0);
      }
  }

  // epilogue: O /= l, store cat[b, t, h*64 + d]
  u16* ob = cat + (long)(b * 2048) * 1024 + h * 64;
#pragma unroll
  for (int st = 0; st < 2; ++st) {
    int trow = blockIdx.x * 128 + wave * 32 + st * 16 + lq * 4;
#pragma unroll
    for (int r = 0; r < 4; ++r) {
      float inv = 1.0f / l_i[st][r];
#pragma unroll
      for (int nt = 0; nt < 4; ++nt)
        ob[(long)(trow + r) * 1024 + nt * 16 + lr] = f2bf(o[st][nt][r] * inv);
    }
  }
}

// ---------------------------------------------------------------------------
// out[row0+row] = res[row] + LN(y[row]) * g + b.
// res_raw: res is a raw input (dtype per flag).  final_out: out dtype per flag.
// ---------------------------------------------------------------------------
__global__ __launch_bounds__(256) void ln_residual(
    const float* __restrict__ y, const void* __restrict__ res, int res_raw,
    const u16* __restrict__ g, const u16* __restrict__ bb,
    void* __restrict__ out, const int* __restrict__ flagp, int final_out,
    long row0) {
  const long row = blockIdx.x;
  const int tid = threadIdx.x, wave = tid >> 6, lane = tid & 63;
  float4 v = ((const float4*)(y + row * 1024))[tid];
  float s1 = v.x + v.y + v.z + v.w;
  float s2 = v.x * v.x + v.y * v.y + v.z * v.z + v.w * v.w;
#pragma unroll
  for (int off = 1; off < 64; off <<= 1) {
    s1 += __shfl_xor(s1, off, 64);
    s2 += __shfl_xor(s2, off, 64);
  }
  __shared__ float ws1[4], ws2[4];
  if (lane == 0) { ws1[wave] = s1; ws2[wave] = s2; }
  __syncthreads();
  float t1 = ws1[0] + ws1[1] + ws1[2] + ws1[3];
  float t2 = ws2[0] + ws2[1] + ws2[2] + ws2[3];
  float mu = t1 * (1.0f / 1024.0f);
  float var = t2 * (1.0f / 1024.0f) - mu * mu;
  float rstd = rsqrtf(var + 1e-5f);
  int i = tid * 4;
  float yy[4] = {v.x, v.y, v.z, v.w};
  bool f32in = res_raw && (*flagp);
  bool f32out = final_out && (*flagp);
  long orow = row0 + row;
  long rrow = res_raw ? orow : row;  // raw res indexed by absolute row
#pragma unroll
  for (int j = 0; j < 4; ++j) {
    float rv = f32in ? ((const float*)res)[rrow * 1024 + i + j]
                     : bf2f(((const u16*)res)[rrow * 1024 + i + j]);
    float o = rv + (yy[j] - mu) * rstd * bf2f(g[i + j]) + bf2f(bb[i + j]);
    if (f32out)
      ((float*)out)[orow * 1024 + i + j] = o;
    else
      ((u16*)out)[orow * 1024 + i + j] = f2bf(o);
  }
}

// ---------------------------------------------------------------------------
extern "C" void kernel_launch(void* const* d_in, const int* in_sizes, int n_in,
                              void* d_out, int out_size, void* d_ws,
                              size_t ws_size, hipStream_t stream) {
  const void* x_raw = d_in[0];
  const void* Wq = d_in[1];
  const void* Wk = d_in[2];
  const void* Wv = d_in[3];
  const void* Wo = d_in[4];
  const void* bo = d_in[5];
  const void* ln1g = d_in[6];
  const void* ln1b = d_in[7];
  const void* W1 = d_in[8];
  const void* b1 = d_in[9];
  const void* W2 = d_in[10];
  const void* b2 = d_in[11];
  const void* ln2g = d_in[12];
  const void* ln2b = d_in[13];

  char* ws = (char*)d_ws;
  // [0,48M): qkv -> mha f32(32M) -> h1c(32M)+ffc(16M).  [48,64M): cat.
  // [64,80M): KF (dead after flash) -> x1.  [80,96M): xb (dead after QKV
  // gemm) -> VF.  [96M..): weights (proven layout from round 3).
  u16* qkv = (u16*)(ws + 0);              // [8192,3072]
  float* mha = (float*)(ws + 0);          // [8192,1024]
  u16* h1c = (u16*)(ws + 0);              // [4096,4096] chunk
  float* ffc = (float*)(ws + 33554432);   // [4096,1024] chunk
  u16* cat = (u16*)(ws + 50331648);       // [8192,1024]
  u16* KF = (u16*)(ws + 67108864);        // frag-order K (16M)
  u16* x1 = (u16*)(ws + 67108864);        // [8192,1024] after flash
  u16* xb = (u16*)(ws + 83886080);        // bf16 x (dead after QKV gemm)
  u16* VF = (u16*)(ws + 83886080);        // frag-order V (16M)
  u16* wqkvt = (u16*)(ws + 100663296);    // [3072,1024]
  u16* wot = (u16*)(ws + 106954752);      // [1024,1024]
  u16* w1t = (u16*)(ws + 109051904);      // [4096,1024]
  u16* w2t = (u16*)(ws + 117440512);      // [1024,4096]
  u16* vecs = (u16*)(ws + 125829120);     // packed bias/gain vectors
  int* flag = (int*)(ws + 125853696);     // dtype flag (1 = fp32)
  // total ~120 MB (proven in round 3)

  const u16* v_bo = vecs + 0;
  const u16* v_l1g = vecs + 1024;
  const u16* v_l1b = vecs + 2048;
  const u16* v_b1 = vecs + 3072;
  const u16* v_b2 = vecs + 7168;
  const u16* v_l2g = vecs + 8192;
  const u16* v_l2b = vecs + 9216;

  detect_dtype<<<1, 256, 0, stream>>>((const u16*)x_raw, flag);
  cvt_copy<<<8192, 256, 0, stream>>>(x_raw, xb, flag, 8388608L);
  cvt_vecs<<<7, 256, 0, stream>>>(bo, ln1g, ln1b, b1, b2, ln2g, ln2b, vecs, flag);

  dim3 tb(32, 8);
  transpose_cvt<<<dim3(2, 32, 16), tb, 0, stream>>>(Wq, wqkvt, 1024, 64, 65536, 65536, flag);
  transpose_cvt<<<dim3(2, 32, 16), tb, 0, stream>>>(Wk, wqkvt + 1048576, 1024, 64, 65536, 65536, flag);
  transpose_cvt<<<dim3(2, 32, 16), tb, 0, stream>>>(Wv, wqkvt + 2097152, 1024, 64, 65536, 65536, flag);
  transpose_cvt<<<dim3(32, 32, 1), tb, 0, stream>>>(Wo, wot, 1024, 1024, 0, 0, flag);
  transpose_cvt<<<dim3(128, 32, 1), tb, 0, stream>>>(W1, w1t, 1024, 4096, 0, 0, flag);
  transpose_cvt<<<dim3(32, 128, 1), tb, 0, stream>>>(W2, w2t, 4096, 1024, 0, 0, flag);

  // qkv = xb @ Wqkv   (xb dead afterwards -> VF may overwrite)
  gemm_bt<0><<<dim3(64, 24), 256, 0, stream>>>(xb, wqkvt, nullptr, qkv, 8192, 3072, 1024);
  // K/V -> MFMA fragment order
  kv_frag<<<dim3(32, 64), 256, 0, stream>>>(qkv, KF, VF);
  // cat = attention
  flash_attn<<<dim3(16, 64), 256, 0, stream>>>(qkv, KF, VF, cat);
  // mha = cat @ Wo + bo (f32)
  gemm_bt<1><<<dim3(64, 8), 256, 0, stream>>>(cat, wot, v_bo, mha, 8192, 1024, 1024);
  // x1 = x_raw + LN(mha)
  ln_residual<<<8192, 256, 0, stream>>>(mha, x_raw, 1, v_l1g, v_l1b, x1, flag, 0, 0);

  // FFN in 2 row-chunks of 4096
  for (int c = 0; c < 2; ++c) {
    const u16* x1c = x1 + (long)c * 4096 * 1024;
    gemm_bt<2><<<dim3(32, 32), 256, 0, stream>>>(x1c, w1t, v_b1, h1c, 4096, 4096, 1024);
    gemm_bt<1><<<dim3(32, 8), 256, 0, stream>>>(h1c, w2t, v_b2, ffc, 4096, 1024, 4096);
    ln_residual<<<4096, 256, 0, stream>>>(ffc, x1c, 0, v_l2g, v_l2b, d_out, flag, 1,
                                          (long)c * 4096);
  }
}

// Round 6
// 652.378 us; speedup vs baseline: 1.7044x; 1.3164x over previous
//
#include <hip/hip_runtime.h>
#include <math.h>

// ---------------------------------------------------------------------------
// Encoder block on MI355X (gfx950).  B=4, T=2048, E=1024, H=16, Dh=64, FF=4096.
// Inputs may be bf16 or fp32 (harness-dependent, detector-classified).
// Attention v6: transposed-score flash (S^T = K·Q^T via operand swap) ->
// per-lane softmax (no shuffles in loop), static-max exp2, deferred l
// reduction, packed bf16x4 LDS writes.  K/V pre-swizzled to fragment order.
// ---------------------------------------------------------------------------

using u16 = unsigned short;
typedef __bf16 bf16x8 __attribute__((ext_vector_type(8)));
typedef __bf16 bf16x4 __attribute__((ext_vector_type(4)));
typedef unsigned short u16x8 __attribute__((ext_vector_type(8)));
typedef unsigned short u16x4 __attribute__((ext_vector_type(4)));
typedef float f32x4 __attribute__((ext_vector_type(4)));

#if defined(__has_builtin)
#if __has_builtin(__builtin_amdgcn_exp2f)
#define EXP2F(x) __builtin_amdgcn_exp2f(x)
#endif
#endif
#ifndef EXP2F
#define EXP2F(x) __expf((x) * 0.69314718055994531f)
#endif

__device__ __forceinline__ float bf2f(u16 h) {
  return __uint_as_float(((unsigned int)h) << 16);
}
__device__ __forceinline__ u16 f2bf(float f) {  // RNE
  unsigned int u = __float_as_uint(f);
  u += 0x7fffu + ((u >> 16) & 1u);
  return (u16)(u >> 16);
}

__device__ __forceinline__ void gload_lds16(const void* g, void* l) {
  __builtin_amdgcn_global_load_lds(
      (__attribute__((address_space(1))) void*)(g),
      (__attribute__((address_space(3))) void*)(l), 16, 0, 0);
}

// ---------------------------------------------------------------------------
// Dtype detector (flag=1 -> fp32 inputs).
// ---------------------------------------------------------------------------
__global__ __launch_bounds__(256) void detect_dtype(const u16* __restrict__ x,
                                                    int* __restrict__ flag) {
  __shared__ int cnt[256];
  int c = 0;
#pragma unroll
  for (int j = 0; j < 8; ++j) {
    float v = bf2f(x[threadIdx.x * 8 + j]);
    float a = fabsf(v);
    if (a >= 1e-4f && a <= 64.0f) ++c;
  }
  cnt[threadIdx.x] = c;
  __syncthreads();
  if (threadIdx.x == 0) {
    int t = 0;
    for (int i = 0; i < 256; ++i) t += cnt[i];
    flag[0] = (t < 1638) ? 1 : 0;
  }
}

__global__ __launch_bounds__(256) void cvt_copy(const void* __restrict__ in,
                                                u16* __restrict__ out,
                                                const int* __restrict__ flagp,
                                                long n) {
  long idx = ((long)blockIdx.x * 256 + threadIdx.x) * 4;
  if (idx >= n) return;
  if (*flagp) {
    float4 v = *(const float4*)((const float*)in + idx);
    out[idx] = f2bf(v.x); out[idx + 1] = f2bf(v.y);
    out[idx + 2] = f2bf(v.z); out[idx + 3] = f2bf(v.w);
  } else {
    *(u16x4*)(out + idx) = *(const u16x4*)((const u16*)in + idx);
  }
}

__global__ __launch_bounds__(256) void cvt_vecs(
    const void* s0, const void* s1, const void* s2, const void* s3,
    const void* s4, const void* s5, const void* s6, u16* __restrict__ dst,
    const int* __restrict__ flagp) {
  const int lens[7] = {1024, 1024, 1024, 4096, 1024, 1024, 1024};
  const int offs[7] = {0, 1024, 2048, 3072, 7168, 8192, 9216};
  const void* srcs[7] = {s0, s1, s2, s3, s4, s5, s6};
  int w = blockIdx.x;
  int f = *flagp;
  for (int i = threadIdx.x; i < lens[w]; i += 256)
    dst[offs[w] + i] = f ? f2bf(((const float*)srcs[w])[i])
                         : ((const u16*)srcs[w])[i];
}

// ---------------------------------------------------------------------------
// Batched transpose + convert: out[b][c*R+r] = cvt(in[b][r*C+c]).
// ---------------------------------------------------------------------------
__global__ __launch_bounds__(256) void transpose_cvt(
    const void* __restrict__ in, u16* __restrict__ out, int R, int C,
    long inBS, long outBS, const int* __restrict__ flagp) {
  __shared__ u16 tile[32][33];
  int f = *flagp;
  u16* ob = out + (long)blockIdx.z * outBS;
  int c = blockIdx.x * 32 + threadIdx.x;
  int r0 = blockIdx.y * 32;
  if (f) {
    const float* ib = (const float*)in + (long)blockIdx.z * inBS;
#pragma unroll
    for (int i = threadIdx.y; i < 32; i += 8)
      tile[i][threadIdx.x] = f2bf(ib[(long)(r0 + i) * C + c]);
  } else {
    const u16* ib = (const u16*)in + (long)blockIdx.z * inBS;
#pragma unroll
    for (int i = threadIdx.y; i < 32; i += 8)
      tile[i][threadIdx.x] = ib[(long)(r0 + i) * C + c];
  }
  __syncthreads();
  int r = r0 + threadIdx.x;
  int c0 = blockIdx.x * 32;
#pragma unroll
  for (int i = threadIdx.y; i < 32; i += 8)
    ob[(long)(c0 + i) * R + r] = tile[threadIdx.x][i];
}

// ---------------------------------------------------------------------------
// Pre-swizzle K and V into MFMA fragment order.
// KF/VF layout: [(bh*32 + jblk)*8 + f][lane][8] u16, f = kt*4 + nt.
//   KF elem j = K[b, t=j0+nt*16+(lane&15), d=kt*32+(lane>>4)*8+j]
//   VF elem j = V[b, t=j0+kt*32+(lane>>4)*8+j, d=nt*16+(lane&15)]
// ---------------------------------------------------------------------------
__global__ __launch_bounds__(256) void kv_frag(const u16* __restrict__ qkv,
                                               u16* __restrict__ KF,
                                               u16* __restrict__ VF) {
  __shared__ u16 Kt[64][72];
  __shared__ u16 Vt[64][72];
  const int jblk = blockIdx.x, bh = blockIdx.y;
  const int b = bh >> 4, h = bh & 15;
  const int tid = threadIdx.x;
  const long j0 = jblk * 64;

  {
    int tt = tid >> 2, c0 = (tid & 3) * 16;
    const u16* src = qkv + (long)(b * 2048 + j0 + tt) * 3072 + h * 64 + c0;
    *(u16x8*)(&Kt[tt][c0]) = *(const u16x8*)(src + 1024);
    *(u16x8*)(&Kt[tt][c0 + 8]) = *(const u16x8*)(src + 1024 + 8);
    *(u16x8*)(&Vt[tt][c0]) = *(const u16x8*)(src + 2048);
    *(u16x8*)(&Vt[tt][c0 + 8]) = *(const u16x8*)(src + 2048 + 8);
  }
  __syncthreads();

  long obase = ((long)bh * 32 + jblk) * 8 * 512;
#pragma unroll
  for (int si = 0; si < 2; ++si) {
    int s = tid * 2 + si;
    int f = s >> 6, ln = s & 63;
    int kt = f >> 2, nt = f & 3;
    int lr = ln & 15, lq = ln >> 4;
    u16x8 ko, vo;
#pragma unroll
    for (int j = 0; j < 8; ++j) {
      ko[j] = Kt[nt * 16 + lr][kt * 32 + lq * 8 + j];
      vo[j] = Vt[kt * 32 + lq * 8 + j][nt * 16 + lr];
    }
    *(u16x8*)(KF + obase + (long)s * 8) = ko;
    *(u16x8*)(VF + obase + (long)s * 8) = vo;
  }
}

// ---------------------------------------------------------------------------
// GEMM: C[M,N] = A[M,K] @ Bt[N,K]^T (+ epilogue).  m97 structure.
// EPI 0: bf16.  EPI 2: +bias, gelu, bf16.  EPI 3: +bias, bf16.
// ---------------------------------------------------------------------------
template <int EPI>
__global__ __launch_bounds__(256) void gemm_bt(
    const u16* __restrict__ A, const u16* __restrict__ Bt,
    const u16* __restrict__ bias, void* __restrict__ Cout,
    int M, int N, int K) {
  __shared__ u16 As[128 * 32];
  __shared__ u16 Bs[128 * 32];
  const int tid = threadIdx.x;
  const int wave = tid >> 6, lane = tid & 63;
  const int m0 = blockIdx.x * 128, n0 = blockIdx.y * 128;
  const int wm = (wave >> 1) * 64, wn = (wave & 1) * 64;
  const int srow = lane >> 2, skoff = (lane & 3) * 8;

  const u16* ag[2];
  const u16* bg[2];
  u16* al[2];
  u16* bl[2];
#pragma unroll
  for (int p = 0; p < 2; ++p) {
    int r = p * 64 + wave * 16;
    ag[p] = A + (long)(m0 + r + srow) * K + skoff;
    bg[p] = Bt + (long)(n0 + r + srow) * K + skoff;
    al[p] = As + r * 32;
    bl[p] = Bs + r * 32;
  }

  f32x4 acc[4][4] = {};
  const int lr = lane & 15, lk = (lane >> 4) * 8;

  for (int k0 = 0; k0 < K; k0 += 32) {
#pragma unroll
    for (int p = 0; p < 2; ++p) {
      gload_lds16(ag[p] + k0, al[p]);
      gload_lds16(bg[p] + k0, bl[p]);
    }
    __syncthreads();
    bf16x8 af[4], bfr[4];
#pragma unroll
    for (int t = 0; t < 4; ++t) {
      af[t] = *(const bf16x8*)(As + (wm + t * 16 + lr) * 32 + lk);
      bfr[t] = *(const bf16x8*)(Bs + (wn + t * 16 + lr) * 32 + lk);
    }
#pragma unroll
    for (int mt = 0; mt < 4; ++mt)
#pragma unroll
      for (int nt = 0; nt < 4; ++nt)
        acc[mt][nt] = __builtin_amdgcn_mfma_f32_16x16x32_bf16(
            af[mt], bfr[nt], acc[mt][nt], 0, 0, 0);
    __syncthreads();
  }

  const int rq = (lane >> 4) * 4, cl = lane & 15;
#pragma unroll
  for (int mt = 0; mt < 4; ++mt)
#pragma unroll
    for (int nt = 0; nt < 4; ++nt) {
      int col = n0 + wn + nt * 16 + cl;
#pragma unroll
      for (int r = 0; r < 4; ++r) {
        long row = (long)(m0 + wm + mt * 16 + rq + r);
        float v = acc[mt][nt][r];
        if (EPI == 0) {
          ((u16*)Cout)[row * N + col] = f2bf(v);
        } else if (EPI == 2) {
          v += bf2f(bias[col]);
          v = 0.5f * v * (1.0f + erff(v * 0.70710678118654752f));
          ((u16*)Cout)[row * N + col] = f2bf(v);
        } else {
          v += bf2f(bias[col]);
          ((u16*)Cout)[row * N + col] = f2bf(v);
        }
      }
    }
}

// ---------------------------------------------------------------------------
// Flash attention v6 (transposed scores).  Grid (T/128, B*H), block 256.
// Each wave: 32 Q-rows (2 strips).  S^T = K·Q^T via mfma(bk, aq) — each lane
// then holds 16 scores of ONE row -> per-lane softmax, no shuffles in loop.
// p = exp2(s' - 3*log2e), Q pre-scaled by log2e/8; l deferred to epilogue.
// ---------------------------------------------------------------------------
__global__ __launch_bounds__(256) void flash_attn(
    const u16* __restrict__ qkv, const u16* __restrict__ KF,
    const u16* __restrict__ VF, u16* __restrict__ cat) {
  const int T = 2048, LD = 3072;
  const float QSCALE = 0.18033688011112042f;  // log2e / 8
  const float EXPC = 4.3280851226677321f;     // 3 * log2e (static max)
  const int bh = blockIdx.y;
  const int b = bh >> 4, h = bh & 15;
  const int tid = threadIdx.x, wave = tid >> 6, lane = tid & 63;
  const int lr = lane & 15, lq = lane >> 4;

  __shared__ u16 Ps[4 * 32 * 72];  // per-wave 32 rows x 64 keys (stride 72)
  u16* Pw = Ps + wave * 32 * 72;

  const u16* Qb = qkv + (long)(b * 2048) * LD + h * 64;
  const long fbase = (long)bh * 32 * 8 * 512;

  // Q fragments (dual-use A/B layout), pre-scaled by log2e/8
  bf16x8 aq[2][2];
#pragma unroll
  for (int st = 0; st < 2; ++st) {
    int qrow = blockIdx.x * 128 + wave * 32 + st * 16 + lr;
#pragma unroll
    for (int kt = 0; kt < 2; ++kt) {
      u16x8 q = *(const u16x8*)(Qb + (long)qrow * LD + kt * 32 + lq * 8);
      bf16x8 t;
#pragma unroll
      for (int j = 0; j < 8; ++j) t[j] = (__bf16)(bf2f(q[j]) * QSCALE);
      aq[st][kt] = t;
    }
  }

  f32x4 o[2][4] = {};
  float lsum[2] = {0.0f, 0.0f};

  for (int jblk = 0; jblk < T / 64; ++jblk) {
    const u16* kf = KF + fbase + (long)jblk * 8 * 512;
    const u16* vf = VF + fbase + (long)jblk * 8 * 512;

    // K fragments (coalesced 16B/lane); used as A-operand (A/B layouts match)
    bf16x8 bk[2][4];
#pragma unroll
    for (int kt = 0; kt < 2; ++kt)
#pragma unroll
      for (int nt = 0; nt < 4; ++nt)
        bk[kt][nt] = *(const bf16x8*)(kf + (kt * 4 + nt) * 512 + lane * 8);

    // S^T tiles: D[m=key][n=qrow]; lane holds keys nt*16+lq*4+r of row lr
    f32x4 s[2][4] = {};
#pragma unroll
    for (int st = 0; st < 2; ++st)
#pragma unroll
      for (int nt = 0; nt < 4; ++nt)
#pragma unroll
        for (int kt = 0; kt < 2; ++kt)
          s[st][nt] = __builtin_amdgcn_mfma_f32_16x16x32_bf16(
              bk[kt][nt], aq[st][kt], s[st][nt], 0, 0, 0);

    // V fragments issued early (latency hidden behind exp/pack VALU)
    bf16x8 bv[2][4];
#pragma unroll
    for (int kt = 0; kt < 2; ++kt)
#pragma unroll
      for (int nt = 0; nt < 4; ++nt)
        bv[kt][nt] = *(const bf16x8*)(vf + (kt * 4 + nt) * 512 + lane * 8);

    // per-lane static-max softmax + packed P^T write (row lr, 4 keys/write)
#pragma unroll
    for (int st = 0; st < 2; ++st)
#pragma unroll
      for (int nt = 0; nt < 4; ++nt) {
        f32x4 p;
#pragma unroll
        for (int r = 0; r < 4; ++r) p[r] = EXP2F(s[st][nt][r] - EXPC);
        lsum[st] += (p[0] + p[1]) + (p[2] + p[3]);
        bf16x4 pk;
#pragma unroll
        for (int r = 0; r < 4; ++r) pk[r] = (__bf16)p[r];
        *(bf16x4*)(Pw + (st * 16 + lr) * 72 + nt * 16 + lq * 4) = pk;
      }

    // O += P @ V  (A-frag rows from Pw, same-wave lgkmcnt ordering)
#pragma unroll
    for (int st = 0; st < 2; ++st)
#pragma unroll
      for (int kt = 0; kt < 2; ++kt) {
        bf16x8 ap =
            *(const bf16x8*)(Pw + (st * 16 + lr) * 72 + kt * 32 + lq * 8);
#pragma unroll
        for (int nt = 0; nt < 4; ++nt)
          o[st][nt] = __builtin_amdgcn_mfma_f32_16x16x32_bf16(
              ap, bv[kt][nt], o[st][nt], 0, 0, 0);
      }
  }

  // deferred l: row-lr total = sum over the 4 lanes sharing lr
#pragma unroll
  for (int st = 0; st < 2; ++st) {
    lsum[st] += __shfl_xor(lsum[st], 16, 64);
    lsum[st] += __shfl_xor(lsum[st], 32, 64);
  }

  // epilogue: O row = lq*4+r, col d = nt*16+lr
  u16* ob = cat + (long)(b * 2048) * 1024 + h * 64;
#pragma unroll
  for (int st = 0; st < 2; ++st) {
    int trow = blockIdx.x * 128 + wave * 32 + st * 16 + lq * 4;
#pragma unroll
    for (int r = 0; r < 4; ++r) {
      float linv = 1.0f / __shfl(lsum[st], lq * 4 + r, 64);
#pragma unroll
      for (int nt = 0; nt < 4; ++nt)
        ob[(long)(trow + r) * 1024 + nt * 16 + lr] = f2bf(o[st][nt][r] * linv);
    }
  }
}

// ---------------------------------------------------------------------------
// out[row] = res[row] + LN(y[row]) * g + b.   y is bf16.
// res_raw: res is a raw input (dtype per flag).  final_out: out dtype per flag.
// ---------------------------------------------------------------------------
__global__ __launch_bounds__(256) void ln_residual(
    const u16* __restrict__ y, const void* __restrict__ res, int res_raw,
    const u16* __restrict__ g, const u16* __restrict__ bb,
    void* __restrict__ out, const int* __restrict__ flagp, int final_out) {
  const long row = blockIdx.x;
  const int tid = threadIdx.x, wave = tid >> 6, lane = tid & 63;
  u16x4 yv = *(const u16x4*)(y + row * 1024 + tid * 4);
  float yy[4];
#pragma unroll
  for (int j = 0; j < 4; ++j) yy[j] = bf2f(yv[j]);
  float s1 = yy[0] + yy[1] + yy[2] + yy[3];
  float s2 = yy[0] * yy[0] + yy[1] * yy[1] + yy[2] * yy[2] + yy[3] * yy[3];
#pragma unroll
  for (int off = 1; off < 64; off <<= 1) {
    s1 += __shfl_xor(s1, off, 64);
    s2 += __shfl_xor(s2, off, 64);
  }
  __shared__ float ws1[4], ws2[4];
  if (lane == 0) { ws1[wave] = s1; ws2[wave] = s2; }
  __syncthreads();
  float t1 = ws1[0] + ws1[1] + ws1[2] + ws1[3];
  float t2 = ws2[0] + ws2[1] + ws2[2] + ws2[3];
  float mu = t1 * (1.0f / 1024.0f);
  float var = t2 * (1.0f / 1024.0f) - mu * mu;
  float rstd = rsqrtf(var + 1e-5f);
  int i = tid * 4;
  bool f32in = res_raw && (*flagp);
  bool f32out = final_out && (*flagp);
#pragma unroll
  for (int j = 0; j < 4; ++j) {
    float rv = f32in ? ((const float*)res)[row * 1024 + i + j]
                     : bf2f(((const u16*)res)[row * 1024 + i + j]);
    float o = rv + (yy[j] - mu) * rstd * bf2f(g[i + j]) + bf2f(bb[i + j]);
    if (f32out)
      ((float*)out)[row * 1024 + i + j] = o;
    else
      ((u16*)out)[row * 1024 + i + j] = f2bf(o);
  }
}

// ---------------------------------------------------------------------------
extern "C" void kernel_launch(void* const* d_in, const int* in_sizes, int n_in,
                              void* d_out, int out_size, void* d_ws,
                              size_t ws_size, hipStream_t stream) {
  const void* x_raw = d_in[0];
  const void* Wq = d_in[1];
  const void* Wk = d_in[2];
  const void* Wv = d_in[3];
  const void* Wo = d_in[4];
  const void* bo = d_in[5];
  const void* ln1g = d_in[6];
  const void* ln1b = d_in[7];
  const void* W1 = d_in[8];
  const void* b1 = d_in[9];
  const void* W2 = d_in[10];
  const void* b2 = d_in[11];
  const void* ln2g = d_in[12];
  const void* ln2b = d_in[13];

  char* ws = (char*)d_ws;
  // Liveness-checked alias map (all bf16 intermediates now):
  //  [0,48M):  qkv (dead after flash) -> mha[0,16M) (dead after ln1)
  //            -> h1[0,64M) spans into cat region
  //  [48,64M): cat (dead after Wo gemm) -> tail of h1
  //  [64,80M): KF (dead after flash) -> ff[64,80M)
  //  [80,96M): xb (dead after QKV gemm) -> VF (dead after flash) -> x1
  //  [96M...): weights / vecs / flag
  u16* qkv = (u16*)(ws + 0);              // [8192,3072]
  u16* mha = (u16*)(ws + 0);              // [8192,1024] bf16
  u16* h1 = (u16*)(ws + 0);               // [8192,4096] bf16
  u16* cat = (u16*)(ws + 50331648);       // [8192,1024]
  u16* KF = (u16*)(ws + 67108864);        // frag-order K (16M)
  u16* ff = (u16*)(ws + 67108864);        // [8192,1024] bf16
  u16* xb = (u16*)(ws + 83886080);        // bf16 x
  u16* VF = (u16*)(ws + 83886080);        // frag-order V (16M)
  u16* x1 = (u16*)(ws + 83886080);        // [8192,1024] after flash
  u16* wqkvt = (u16*)(ws + 100663296);    // [3072,1024]
  u16* wot = (u16*)(ws + 106954752);      // [1024,1024]
  u16* w1t = (u16*)(ws + 109051904);      // [4096,1024]
  u16* w2t = (u16*)(ws + 117440512);      // [1024,4096]
  u16* vecs = (u16*)(ws + 125829120);     // packed bias/gain vectors
  int* flag = (int*)(ws + 125853696);     // dtype flag (1 = fp32)

  const u16* v_bo = vecs + 0;
  const u16* v_l1g = vecs + 1024;
  const u16* v_l1b = vecs + 2048;
  const u16* v_b1 = vecs + 3072;
  const u16* v_b2 = vecs + 7168;
  const u16* v_l2g = vecs + 8192;
  const u16* v_l2b = vecs + 9216;

  detect_dtype<<<1, 256, 0, stream>>>((const u16*)x_raw, flag);
  cvt_copy<<<8192, 256, 0, stream>>>(x_raw, xb, flag, 8388608L);
  cvt_vecs<<<7, 256, 0, stream>>>(bo, ln1g, ln1b, b1, b2, ln2g, ln2b, vecs, flag);

  dim3 tb(32, 8);
  transpose_cvt<<<dim3(2, 32, 16), tb, 0, stream>>>(Wq, wqkvt, 1024, 64, 65536, 65536, flag);
  transpose_cvt<<<dim3(2, 32, 16), tb, 0, stream>>>(Wk, wqkvt + 1048576, 1024, 64, 65536, 65536, flag);
  transpose_cvt<<<dim3(2, 32, 16), tb, 0, stream>>>(Wv, wqkvt + 2097152, 1024, 64, 65536, 65536, flag);
  transpose_cvt<<<dim3(32, 32, 1), tb, 0, stream>>>(Wo, wot, 1024, 1024, 0, 0, flag);
  transpose_cvt<<<dim3(128, 32, 1), tb, 0, stream>>>(W1, w1t, 1024, 4096, 0, 0, flag);
  transpose_cvt<<<dim3(32, 128, 1), tb, 0, stream>>>(W2, w2t, 4096, 1024, 0, 0, flag);

  // qkv = xb @ Wqkv   (xb dead afterwards)
  gemm_bt<0><<<dim3(64, 24), 256, 0, stream>>>(xb, wqkvt, nullptr, qkv, 8192, 3072, 1024);
  // K/V -> MFMA fragment order
  kv_frag<<<dim3(32, 64), 256, 0, stream>>>(qkv, KF, VF);
  // cat = attention
  flash_attn<<<dim3(16, 64), 256, 0, stream>>>(qkv, KF, VF, cat);
  // mha = cat @ Wo + bo (bf16)
  gemm_bt<3><<<dim3(64, 8), 256, 0, stream>>>(cat, wot, v_bo, mha, 8192, 1024, 1024);
  // x1 = x_raw + LN(mha)
  ln_residual<<<8192, 256, 0, stream>>>(mha, x_raw, 1, v_l1g, v_l1b, x1, flag, 0);
  // h1 = gelu(x1 @ W1 + b1)
  gemm_bt<2><<<dim3(64, 32), 256, 0, stream>>>(x1, w1t, v_b1, h1, 8192, 4096, 1024);
  // ff = h1 @ W2 + b2 (bf16)
  gemm_bt<3><<<dim3(64, 8), 256, 0, stream>>>(h1, w2t, v_b2, ff, 8192, 1024, 4096);
  // out = x1 + LN(ff)
  ln_residual<<<8192, 256, 0, stream>>>(ff, x1, 0, v_l2g, v_l2b, d_out, flag, 1);
}